// Round 13
// baseline (150.724 us; speedup 1.0000x reference)
//
#include <hip/hip_runtime.h>
#include <math.h>

#define TOPK 4
#define NQ 13   // 13 independent float4 loads = 52-float window (mean seg 32 + ~3.5 sigma)

// One thread per node; whole segment loaded as NQ INDEPENDENT float4s issued
// back-to-back, then one masked consume pass. sched_barrier(0) between the
// two loops pins the schedule: no load may sink past it into the consume
// chain (R11: compiler kept only ~6 quads live, VGPR=40, serialized waits).
// __launch_bounds__(256,4) caps VGPR at 128 -> 16 waves/CU.
__global__ __launch_bounds__(256, 4) void segment_top4_kernel(
    const int* __restrict__ row_ptr,
    const float* __restrict__ scores,
    float* __restrict__ vals_out,   // [N,4] float32
    float* __restrict__ idx_out,    // [N,4] indices as float32
    int n_nodes, int n_edges)
{
    int node = blockIdx.x * 256 + threadIdx.x;
    if (node >= n_nodes) return;

    int sb = row_ptr[node];
    int se = row_ptr[node + 1];
    int lo = sb & ~3;                 // 16B-aligned window start
    int clamp_hi = n_edges - 4;

    // ---- issue all window loads, fully independent, back-to-back ----
    // Clamp keeps every quad in-array. lo and clamp_hi are both multiples of
    // 4, so a clamped quad satisfies lo+4j >= n_edges: all its nominal
    // indices are >= n_edges >= se and the mask below discards them —
    // in-segment elements are never clamped.
    float4 r[NQ];
#pragma unroll
    for (int j = 0; j < NQ; ++j) {
        int src = lo + 4 * j;
        src = src < clamp_hi ? src : clamp_hi;
        r[j] = *(const float4*)(scores + src);
    }
    // Scheduling fence: nothing crosses — all 13 loads issue before any use.
    __builtin_amdgcn_sched_barrier(0);

    float v0 = -INFINITY, v1 = -INFINITY, v2 = -INFINITY, v3 = -INFINITY;
    int   i0 = -1, i1 = -1, i2 = -1, i3 = -1;

    // Branchless insertion, strict '>' keeps the smaller edge index on ties
    // (elements processed in increasing e) — matches reference. -inf never inserts.
    auto ins = [&](float sc, int id) {
        bool g0 = sc > v0, g1 = sc > v1, g2 = sc > v2, g3 = sc > v3;
        v3 = g3 ? (g2 ? v2 : sc) : v3;  i3 = g3 ? (g2 ? i2 : id) : i3;
        v2 = g2 ? (g1 ? v1 : sc) : v2;  i2 = g2 ? (g1 ? i1 : id) : i2;
        v1 = g1 ? (g0 ? v0 : sc) : v1;  i1 = g1 ? (g0 ? i0 : id) : i1;
        v0 = g0 ? sc : v0;              i0 = g0 ? id : i0;
    };

    // Single-compare in-segment mask: position p (0..51) valid iff
    // (unsigned)(p - off) < len, off = sb-lo in [0,3], len = se-sb.
    unsigned off = (unsigned)(sb - lo);
    unsigned len = (unsigned)(se - sb);
#pragma unroll
    for (int j = 0; j < NQ; ++j) {
        int p = 4 * j;
        ins((unsigned)(p     - off) < len ? r[j].x : -INFINITY, lo + p);
        ins((unsigned)(p + 1 - off) < len ? r[j].y : -INFINITY, lo + p + 1);
        ins((unsigned)(p + 2 - off) < len ? r[j].z : -INFINITY, lo + p + 2);
        ins((unsigned)(p + 3 - off) < len ? r[j].w : -INFINITY, lo + p + 3);
    }
    // Tail for segments longer than the window (~1e-3 of nodes; lines are
    // L1/L2-hot from neighboring lanes' windows).
    for (int e = lo + 4 * NQ; e < se; ++e) ins(scores[e], e);

    float4 vo = make_float4(v0, v1, v2, v3);
    *(float4*)(vals_out + (size_t)node * 4) = vo;
    float4 io = make_float4((float)i0, (float)i1, (float)i2, (float)i3);
    *(float4*)(idx_out + (size_t)node * 4) = io;
}

extern "C" void kernel_launch(void* const* d_in, const int* in_sizes, int n_in,
                              void* d_out, int out_size, void* d_ws, size_t ws_size,
                              hipStream_t stream)
{
    const int*   row_ptr = (const int*)d_in[0];
    const float* scores  = (const float*)d_in[1];
    int n_nodes = in_sizes[0] - 1;
    int n_edges = in_sizes[1];

    float* out      = (float*)d_out;
    float* vals_out = out;                           // first N*4 floats
    float* idx_out  = out + (size_t)n_nodes * TOPK;  // next N*4 floats (idx as f32)

    int blocks = (n_nodes + 255) / 256;
    segment_top4_kernel<<<blocks, 256, 0, stream>>>(
        row_ptr, scores, vals_out, idx_out, n_nodes, n_edges);
}